// Round 13
// baseline (274.837 us; speedup 1.0000x reference)
//
#include <hip/hip_runtime.h>
#include <hip/hip_cooperative_groups.h>
#include <hip/hip_bf16.h>
#include <stdint.h>

namespace cg = cooperative_groups;

#define B_SZ 8192
#define D_SZ 512
#define U_SZ 512
#define M_SZ 16
#define K_SZ 64

typedef short bf16x8 __attribute__((ext_vector_type(8)));
typedef float f32x4 __attribute__((ext_vector_type(4)));

__device__ __forceinline__ unsigned short f2bf(float f) {
  union { float f; unsigned u; } v; v.f = f;
  unsigned r = v.u + 0x7fffu + ((v.u >> 16) & 1u);
  return (unsigned short)(r >> 16);
}

// =====================================================================
// poly_fused: ONE cooperative dispatch.
//   pre-phase (prep1 redistributed over 256 blocks):
//     role T: 8 tasks/block (2 at a time via 256-thread halves):
//             kernels f32 -> kbf frag-linear bf16
//     role X: 2 tasks/block: x f32 -> xbf frag-linear bf16 (LDS transpose)
//     role W: blocks 0-7: key_kernel -> wkbf
//   __threadfence() + grid.sync()   [device-scope: cross-XCD visibility]
//   then R12's fused kernel with 3 fixes:
//     - kv stride 65 (was 68: 8-way bank conflict, 1.08M conflicts)
//     - kv moved OUT of ring overlay -> STAGE(0..3) issued BEFORE
//       phase A: ring DMA overlaps keyv-MFMA + sim compute
//     - main loop BYTE-IDENTICAL to R6's proven 80.7us loop.
// LDS map: [0,65536) ring 8x8KB (pre-phase scratch tf2/sx2 overlays it)
//          [65536,132096) kv[256] stride-65 f32
//          [132096,148480) sSim[16][256] | [148480,152576) sBias[16][64]
//          [152576,156672) sKM[16][64]
// 153KB -> 1 block/CU x 256 CU = 256 co-resident blocks = grid. VGPR
// target <=128 under (512,2) (R12: 88, pre-phase is register-light).
// =====================================================================
#define GLL(src_, dst_)                                                        \
  __builtin_amdgcn_global_load_lds(                                            \
      (const __attribute__((address_space(1))) unsigned int*)(src_),           \
      (__attribute__((address_space(3))) unsigned int*)(dst_), 16, 0, 0)

#define STAGE(mode_, kt_, bufi_)                                               \
  {                                                                            \
    const unsigned short* _src = kbf_l +                                       \
        (((size_t)(mode_) * 8 + ut) * 8 + (kt_)) * 4096 + w * 512;             \
    unsigned short* _dst = Bbuf + (bufi_) * 4096 + w * 512;                    \
    GLL(_src, _dst);                                                           \
  }

#define LOAD_AF(dst_, kt_)                                                     \
  _Pragma("unroll") for (int ii = 0; ii < 2; ++ii)                             \
      _Pragma("unroll") for (int h = 0; h < 2; ++h) {                          \
    int g_ = bt * 16 + w * 2 + ii;                                             \
    dst_[ii][h] = *(const bf16x8*)(                                            \
        xbf + ((((size_t)(g_ >> 3) * 8 + (kt_)) * 8 + (g_ & 7)) * 2 + h) *     \
                  512 +                                                        \
              (size_t)l * 8);                                                  \
  }

__global__ __launch_bounds__(512, 2) void poly_fused(
    const float* __restrict__ x, const float* __restrict__ key_kernel,
    const float* __restrict__ key_bias, const float* __restrict__ keys_map,
    const float* __restrict__ kernels, const float* __restrict__ biases,
    unsigned short* __restrict__ xbf, unsigned short* __restrict__ kbf,
    unsigned short* __restrict__ wkbf, float* __restrict__ out) {
  __shared__ __align__(16) char smem[156672];

  int t = threadIdx.x, w = t >> 6, l = t & 63;
  int bid = blockIdx.x;
  int ut = bid & 7, bt = bid >> 3;  // ut: XCD-pinned kbf slice
  int b0 = bt * 256, u0 = ut * 64;
  int lane16 = l & 15, quad = l >> 4;

  unsigned short* Bbuf = (unsigned short*)smem;
  float* kvp = (float*)(smem + 65536);          // [256] stride 65 f32
  float* sSim = (float*)(smem + 132096);
  float* sBias = (float*)(smem + 148480);
  float* sKM = (float*)(smem + 152576);

  // pre-phase scratch overlays the ring region:
  float(*tf2)[32][65] = (float(*)[32][65])smem;                   // 16640 B
  unsigned short(*sx2)[16][520] =
      (unsigned short(*)[16][520])(smem + 16640);                 // 33280 B

  // ================= PRE-PHASE (prep1 redistributed) =================
  {
    int th = t & 255, hs = t >> 8;  // two 256-thread halves

    // ---- role T: 8 tasks/block, 2 concurrent (one per half) ----
#pragma unroll 1
    for (int rep = 0; rep < 4; ++rep) {
      int task = bid * 8 + rep * 2 + hs;  // 0..2047
      int m = task >> 7;
      int rem = task & 127;
      int a = (rem >> 3) & 15;  // d-tile
      int utt = rem & 7;        // u-tile
      int d0 = a * 32;
      {
        int dr = th >> 4, uc = th & 15;
        const float* src =
            kernels + ((size_t)m * D_SZ + d0 + dr) * U_SZ + utt * 64 + uc * 4;
        float4 aa = *(const float4*)src;
        float4 bb = *(const float4*)(src + (size_t)16 * U_SZ);
        tf2[hs][dr][uc * 4 + 0] = aa.x; tf2[hs][dr][uc * 4 + 1] = aa.y;
        tf2[hs][dr][uc * 4 + 2] = aa.z; tf2[hs][dr][uc * 4 + 3] = aa.w;
        tf2[hs][dr + 16][uc * 4 + 0] = bb.x; tf2[hs][dr + 16][uc * 4 + 1] = bb.y;
        tf2[hs][dr + 16][uc * 4 + 2] = bb.z; tf2[hs][dr + 16][uc * 4 + 3] = bb.w;
      }
      __syncthreads();
      {
        int j = th >> 6, lp = th & 63;
        int dc = lp >> 4, l16 = lp & 15;
        int kt0 = a >> 1, h = a & 1;
        int ur = j * 16 + l16;
        unsigned short* dst = kbf +
            (((((size_t)m * 8 + utt) * 8 + kt0) * 4 + j) * 2 + h) * 512 +
            (size_t)lp * 8;
        ushort4 lo, hi;
        lo.x = f2bf(tf2[hs][dc * 8 + 0][ur]); lo.y = f2bf(tf2[hs][dc * 8 + 1][ur]);
        lo.z = f2bf(tf2[hs][dc * 8 + 2][ur]); lo.w = f2bf(tf2[hs][dc * 8 + 3][ur]);
        hi.x = f2bf(tf2[hs][dc * 8 + 4][ur]); hi.y = f2bf(tf2[hs][dc * 8 + 5][ur]);
        hi.z = f2bf(tf2[hs][dc * 8 + 6][ur]); hi.w = f2bf(tf2[hs][dc * 8 + 7][ur]);
        *(ushort4*)dst = lo;
        *(ushort4*)(dst + 4) = hi;
      }
      __syncthreads();
    }

    // ---- role X: 2 tasks/block (one per half) ----
    {
      int task = bid * 2 + hs;  // 0..511
      int btx = task >> 3, i = task & 7;
      int b0x = task * 16;
#pragma unroll
      for (int rep = 0; rep < 8; ++rep) {
        int idx = rep * 256 + th;
        int row = idx >> 7;
        int c4 = (idx & 127) * 4;
        float4 v = *(const float4*)(x + (size_t)(b0x + row) * D_SZ + c4);
        ushort4 o;
        o.x = f2bf(v.x); o.y = f2bf(v.y); o.z = f2bf(v.z); o.w = f2bf(v.w);
        *(ushort4*)(&sx2[hs][row][c4]) = o;
      }
      __syncthreads();
      int w2 = th >> 6, lx = th & 63;
      int ln = lx & 15, qx = lx >> 4;
#pragma unroll
      for (int rep = 0; rep < 4; ++rep) {
        int c = w2 * 4 + rep;
        int ktx = c >> 1, hx = c & 1;
        const unsigned short* srcp = &sx2[hs][ln][ktx * 64 + hx * 32 + qx * 8];
        ushort4 lo = *(const ushort4*)(srcp);
        ushort4 hi = *(const ushort4*)(srcp + 4);
        unsigned short* dst = xbf +
            ((((size_t)btx * 8 + ktx) * 8 + i) * 2 + hx) * 512 + (size_t)lx * 8;
        *(ushort4*)dst = lo;
        *(ushort4*)(dst + 4) = hi;
      }
    }

    // ---- role W: blocks 0-7, all 512 threads ----
    if (bid < 8) {
      int ktw = bid;
      int c = t;
      int j = c >> 7, h = (c >> 6) & 1, qw = (c >> 4) & 3, ln = c & 15;
      int dd = ktw * 64 + h * 32 + qw * 8;
      int u = j * 16 + ln;
      unsigned short v[8];
#pragma unroll
      for (int e = 0; e < 8; ++e)
        v[e] = f2bf(key_kernel[(size_t)(dd + e) * K_SZ + u]);
      unsigned short* dst =
          wkbf + ((size_t)((ktw * 4 + j) * 2 + h) * 64 + qw * 16 + ln) * 8;
#pragma unroll
      for (int e = 0; e < 8; ++e) dst[e] = v[e];
    }
  }

  // device-scope fence + grid-wide barrier: pre-phase writes -> visible
  __threadfence();
  cg::this_grid().sync();

  // ================= FUSED POLY (R12 + fixes) =================
  // stage bias + keys_map
  {
    int bi = t * 2;  // 0..1022
    *(float2*)(sBias + bi) =
        *(const float2*)(biases + (size_t)(bi >> 6) * U_SZ + u0 + (bi & 63));
    if (t < 256) ((float4*)sKM)[t] = ((const float4*)keys_map)[t];
  }

  // issue ring slots 0-3 NOW: DMA overlaps phase A/B compute
  const unsigned short* kbf_l = kbf + (size_t)l * 8;
  STAGE(0, 0, 0);
  STAGE(1, 0, 1);
  STAGE(2, 0, 2);
  STAGE(3, 0, 3);

  // ---- phase A: keyv = xb @ Wk + key_bias -> kvp (stride 65) ----
  {
    f32x4 kacc[2][4];
#pragma unroll
    for (int ii = 0; ii < 2; ++ii)
#pragma unroll
      for (int j = 0; j < 4; ++j) kacc[ii][j] = (f32x4){0.f, 0.f, 0.f, 0.f};
    for (int kt = 0; kt < 8; ++kt) {
      bf16x8 a2[2][2];
      LOAD_AF(a2, kt);
#pragma unroll
      for (int j = 0; j < 4; ++j) {
        bf16x8 w0 = *(const bf16x8*)(wkbf + ((size_t)((kt * 4 + j) * 2 + 0) * 64 + l) * 8);
        bf16x8 w1 = *(const bf16x8*)(wkbf + ((size_t)((kt * 4 + j) * 2 + 1) * 64 + l) * 8);
#pragma unroll
        for (int ii = 0; ii < 2; ++ii) {
          kacc[ii][j] = __builtin_amdgcn_mfma_f32_16x16x32_bf16(a2[ii][0], w0, kacc[ii][j], 0, 0, 0);
          kacc[ii][j] = __builtin_amdgcn_mfma_f32_16x16x32_bf16(a2[ii][1], w1, kacc[ii][j], 0, 0, 0);
        }
      }
    }
#pragma unroll
    for (int j = 0; j < 4; ++j) {
      float bc = key_bias[j * 16 + lane16];
#pragma unroll
      for (int ii = 0; ii < 2; ++ii)
#pragma unroll
        for (int r = 0; r < 4; ++r)
          kvp[(size_t)(w * 32 + ii * 16 + quad * 4 + r) * 65 + j * 16 + lane16] =
              kacc[ii][j][r] + bc;
    }
  }
  __syncthreads();

  // ---- phase B: sim -> sSim[16][256] (stride-65 reads: conflict-free) ----
  {
    int row = t >> 1, mg = (t & 1) * 8;
    float d2[8] = {0.f, 0.f, 0.f, 0.f, 0.f, 0.f, 0.f, 0.f};
#pragma unroll 8
    for (int k = 0; k < 64; ++k) {
      float kvv = kvp[(size_t)row * 65 + k];
#pragma unroll
      for (int q = 0; q < 8; ++q) {
        float df = kvv - sKM[(mg + q) * 64 + k];
        d2[q] += df * df;
      }
    }
#pragma unroll
    for (int q = 0; q < 8; ++q)
      sSim[(mg + q) * 256 + row] = 1.0f / (sqrtf(d2[q]) + 1.0f);
  }

  // ---- ring prologue tail ----
  bf16x8 afc[2][2], afn[2][2];
  LOAD_AF(afc, 0);
  asm volatile("s_waitcnt vmcnt(0)" ::: "memory");
  __syncthreads();

  f32x4 facc[2][4];
#pragma unroll
  for (int i = 0; i < 2; ++i)
#pragma unroll
    for (int j = 0; j < 4; ++j) facc[i][j] = (f32x4){0.f, 0.f, 0.f, 0.f};

  // ---- R6 main loop (byte-identical) ----
#pragma unroll 1
  for (int kt = 0; kt < 8; ++kt) {
#pragma unroll
    for (int mode = 0; mode < 16; ++mode) {
      const int s = kt * 16 + mode;
      {
        int mode4 = (mode + 4) & 15;
        int kt4 = (mode >= 12) ? ((kt + 1) & 7) : kt;
        STAGE(mode4, kt4, (s + 4) & 7);
      }
      if (mode == 0 && kt < 7) { LOAD_AF(afn, kt + 1); }
      if (mode < 5) {
        if (kt < 7)
          asm volatile("s_waitcnt vmcnt(8)" ::: "memory");
        else
          asm volatile("s_waitcnt vmcnt(4)" ::: "memory");
      } else {
        asm volatile("s_waitcnt vmcnt(4)" ::: "memory");
      }
      asm volatile("s_barrier" ::: "memory");

      const unsigned short* lb = Bbuf + (s & 7) * 4096;
      bf16x8 bfr[4][2];
#pragma unroll
      for (int j = 0; j < 4; ++j)
#pragma unroll
        for (int h = 0; h < 2; ++h)
          bfr[j][h] = *(const bf16x8*)(lb + (j * 2 + h) * 512 + (size_t)l * 8);

      f32x4 sv[2];
#pragma unroll
      for (int i = 0; i < 2; ++i)
        sv[i] =
            *(const f32x4*)(sSim + mode * 256 + w * 32 + i * 16 + quad * 4);

#pragma unroll
      for (int i = 0; i < 2; ++i)
#pragma unroll
        for (int j = 0; j < 4; ++j) {
          f32x4 p = __builtin_amdgcn_mfma_f32_16x16x32_bf16(
              afc[i][0], bfr[j][0], (f32x4){0.f, 0.f, 0.f, 0.f}, 0, 0, 0);
          p = __builtin_amdgcn_mfma_f32_16x16x32_bf16(afc[i][1], bfr[j][1], p,
                                                      0, 0, 0);
#pragma unroll
          for (int r = 0; r < 4; ++r) facc[i][j][r] += sv[i][r] * p[r];
        }

      if (kt == 0) {  // sim-weighted bias, once per mode
        float bbv[4];
#pragma unroll
        for (int j = 0; j < 4; ++j)
          bbv[j] = sBias[mode * 64 + j * 16 + lane16];
#pragma unroll
        for (int i = 0; i < 2; ++i)
#pragma unroll
          for (int j = 0; j < 4; ++j)
#pragma unroll
            for (int r = 0; r < 4; ++r) facc[i][j][r] += sv[i][r] * bbv[j];
      }
    }
    if (kt < 7) {
#pragma unroll
      for (int ii = 0; ii < 2; ++ii)
#pragma unroll
        for (int h = 0; h < 2; ++h) afc[ii][h] = afn[ii][h];
    }
  }

  // epilogue: drain wrap-stage DMA, direct store
  asm volatile("s_waitcnt vmcnt(0)" ::: "memory");
#pragma unroll
  for (int i = 0; i < 2; ++i)
#pragma unroll
    for (int r = 0; r < 4; ++r) {
      int row = b0 + w * 32 + i * 16 + quad * 4 + r;
      float* orow = out + (size_t)row * U_SZ + u0;
#pragma unroll
      for (int j = 0; j < 4; ++j)
        orow[j * 16 + lane16] = facc[i][j][r] * 0.0625f;
    }
}

extern "C" void kernel_launch(void* const* d_in, const int* in_sizes, int n_in,
                              void* d_out, int out_size, void* d_ws, size_t ws_size,
                              hipStream_t stream) {
  const float* x = (const float*)d_in[0];
  const float* key_kernel = (const float*)d_in[1];
  const float* key_bias = (const float*)d_in[2];
  const float* keys_map = (const float*)d_in[3];
  const float* kernels = (const float*)d_in[4];
  const float* biases = (const float*)d_in[5];
  float* out = (float*)d_out;

  // ws: xbf 8MB | kbf 8MB | wkbf 64KB
  char* p = (char*)d_ws;
  unsigned short* xbf = (unsigned short*)p;  p += (size_t)B_SZ * D_SZ * 2;
  unsigned short* kbf = (unsigned short*)p;  p += (size_t)M_SZ * U_SZ * D_SZ * 2;
  unsigned short* wkbf = (unsigned short*)p;

  void* kargs[] = {(void*)&x,       (void*)&key_kernel, (void*)&key_bias,
                   (void*)&keys_map, (void*)&kernels,    (void*)&biases,
                   (void*)&xbf,     (void*)&kbf,        (void*)&wkbf,
                   (void*)&out};
  hipLaunchCooperativeKernel((const void*)poly_fused, dim3(256), dim3(512),
                             kargs, 0, stream);
}

// Round 14
// 172.276 us; speedup vs baseline: 1.5953x; 1.5953x over previous
//
#include <hip/hip_runtime.h>
#include <hip/hip_bf16.h>
#include <stdint.h>

#define B_SZ 8192
#define D_SZ 512
#define U_SZ 512
#define M_SZ 16
#define K_SZ 64

typedef short bf16x8 __attribute__((ext_vector_type(8)));
typedef float f32x4 __attribute__((ext_vector_type(4)));

__device__ __forceinline__ unsigned short f2bf(float f) {
  union { float f; unsigned u; } v; v.f = f;
  unsigned r = v.u + 0x7fffu + ((v.u >> 16) & 1u);
  return (unsigned short)(r >> 16);
}

// =====================================================================
// prep1: role-split single launch. ALL outputs are fragment-linear bf16.
//  [0,2048):    kernels [M][D][U] f32 -> kbf [m][ut][kt][j][h][lane][8]
//  [2048,2056): key_kernel [D][K]     -> wkbf [kt][j][h][lane][8]
//  [2056,2568): x [B][D]              -> xbf [bt][kt][i][h][lane][8]
// =====================================================================
__global__ __launch_bounds__(256) void prep1(
    const float* __restrict__ x, const float* __restrict__ key_kernel,
    const float* __restrict__ kernels, unsigned short* __restrict__ xbf,
    unsigned short* __restrict__ kbf, unsigned short* __restrict__ wkbf) {
  __shared__ float tf[32][65];
  __shared__ unsigned short sx[16][520];
  int bid = blockIdx.x;
  int t = threadIdx.x;

  if (bid < 2048) {
    // ---- role T: kernels -> kbf (frag-linear B operand) ----
    int m = bid >> 7;
    int rem = bid & 127;
    int a = (rem >> 3) & 15;  // d-tile (32 d's)
    int ut = rem & 7;         // u-tile (64 u's)
    int d0 = a * 32, u0 = ut * 64;
    {
      int dr = t >> 4, uc = t & 15;
      const float* src = kernels + ((size_t)m * D_SZ + d0 + dr) * U_SZ + u0 + uc * 4;
      float4 aa = *(const float4*)src;
      float4 bb = *(const float4*)(src + (size_t)16 * U_SZ);
      tf[dr][uc * 4 + 0] = aa.x; tf[dr][uc * 4 + 1] = aa.y;
      tf[dr][uc * 4 + 2] = aa.z; tf[dr][uc * 4 + 3] = aa.w;
      tf[dr + 16][uc * 4 + 0] = bb.x; tf[dr + 16][uc * 4 + 1] = bb.y;
      tf[dr + 16][uc * 4 + 2] = bb.z; tf[dr + 16][uc * 4 + 3] = bb.w;
    }
    __syncthreads();
    {
      int j = t >> 6;            // frag col-block 0..3 (== wave id)
      int lp = t & 63;           // frag lane 0..63
      int dc = lp >> 4, lane16 = lp & 15;
      int kt = a >> 1, h = a & 1;
      int ur = j * 16 + lane16;  // u-row 0..63
      unsigned short* dst = kbf +
          (((((size_t)m * 8 + ut) * 8 + kt) * 4 + j) * 2 + h) * 512 +
          (size_t)lp * 8;
      ushort4 lo, hi;
      lo.x = f2bf(tf[dc * 8 + 0][ur]); lo.y = f2bf(tf[dc * 8 + 1][ur]);
      lo.z = f2bf(tf[dc * 8 + 2][ur]); lo.w = f2bf(tf[dc * 8 + 3][ur]);
      hi.x = f2bf(tf[dc * 8 + 4][ur]); hi.y = f2bf(tf[dc * 8 + 5][ur]);
      hi.z = f2bf(tf[dc * 8 + 6][ur]); hi.w = f2bf(tf[dc * 8 + 7][ur]);
      *(ushort4*)dst = lo;
      *(ushort4*)(dst + 4) = hi;
    }
    return;
  }

  if (bid < 2056) {
    // ---- role W: key_kernel -> wkbf ----
    int kt = bid - 2048;
#pragma unroll
    for (int rep = 0; rep < 2; ++rep) {
      int c = rep * 256 + t;
      int j = c >> 7, h = (c >> 6) & 1, quad = (c >> 4) & 3, ln = c & 15;
      int dd = kt * 64 + h * 32 + quad * 8;
      int u = j * 16 + ln;
      unsigned short v[8];
#pragma unroll
      for (int e = 0; e < 8; ++e)
        v[e] = f2bf(key_kernel[(size_t)(dd + e) * K_SZ + u]);
      unsigned short* dst =
          wkbf + ((size_t)((kt * 4 + j) * 2 + h) * 64 + quad * 16 + ln) * 8;
#pragma unroll
      for (int e = 0; e < 8; ++e) dst[e] = v[e];
    }
    return;
  }

  // ---- role X (v2): x -> xbf via LDS transpose, coalesced reads ----
  {
    int xb0 = bid - 2056;            // 0..511, 16 rows each
    int btx = xb0 >> 3, i = xb0 & 7;
    int b0 = xb0 * 16;
#pragma unroll
    for (int rep = 0; rep < 8; ++rep) {
      int idx = rep * 256 + t;       // 0..2047
      int row = idx >> 7;            // 0..15
      int c4 = (idx & 127) * 4;      // 0..508
      float4 v = *(const float4*)(x + (size_t)(b0 + row) * D_SZ + c4);
      ushort4 o;
      o.x = f2bf(v.x); o.y = f2bf(v.y); o.z = f2bf(v.z); o.w = f2bf(v.w);
      *(ushort4*)(&sx[row][c4]) = o;
    }
    __syncthreads();
    int w = t >> 6, l = t & 63;
    int ln = l & 15, quad = l >> 4;
#pragma unroll
    for (int rep = 0; rep < 4; ++rep) {
      int c = w * 4 + rep;           // chunk 0..15 = (kt,h)
      int kt = c >> 1, h = c & 1;
      const unsigned short* srcp = &sx[ln][kt * 64 + h * 32 + quad * 8];
      ushort4 lo = *(const ushort4*)(srcp);
      ushort4 hi = *(const ushort4*)(srcp + 4);
      unsigned short* dst =
          xbf + ((((size_t)btx * 8 + kt) * 8 + i) * 2 + h) * 512 + (size_t)l * 8;
      *(ushort4*)dst = lo;
      *(ushort4*)(dst + 4) = hi;
    }
  }
}

// =====================================================================
// poly_gemm v14: out[b,u] = (1/16) sum_m sim[b,m]*(x@kernels_m+biases_m)
//
// ROUND-14: R12's 2-dispatch fusion + the two regressions FIXED (these
// fixes were validated conceptually in R13 but bundled into the failed
// cooperative experiment; this isolates them on the working structure):
//  FIX 1: kv stride 68 -> 65 (68%32=4 gave 8-way conflicts, 1.08M
//         SQ_LDS_BANK_CONFLICT; 65%32=1 -> phase-B row reads hit
//         distinct banks, phase-A writes <=3 lanes/bank).
//  FIX 2: kv moved OUT of the ring overlay into its own LDS region ->
//         STAGE(0..3) ring DMA issues BEFORE phase A and flies under
//         the keyv-MFMA + sim compute (was serialized after phase B).
// MAIN LOOP BYTE-IDENTICAL TO R6 (proven 80.7us): 256 blocks (32 bt x
// 8 ut XCD-pinned), 512 thr = 8 waves x 32 rows, 16 modes per wave,
// ring 8x8KB lookahead-4, counted vmcnt (8/4, never 0), 1 s_barrier
// per iter, direct-store epilogue.
// LDS map: [0,65536) ring | [65536,132096) kv[256] stride-65 f32 |
// [132096,148480) sSim[16][256] | [148480,152576) sBias[16][64] |
// [152576,156672) sKM[16][64].  153KB -> 1 block/CU (same as R12).
// =====================================================================
#define GLL(src_, dst_)                                                        \
  __builtin_amdgcn_global_load_lds(                                            \
      (const __attribute__((address_space(1))) unsigned int*)(src_),           \
      (__attribute__((address_space(3))) unsigned int*)(dst_), 16, 0, 0)

#define STAGE(mode_, kt_, bufi_)                                               \
  {                                                                            \
    const unsigned short* _src = kbf_l +                                       \
        (((size_t)(mode_) * 8 + ut) * 8 + (kt_)) * 4096 + w * 512;             \
    unsigned short* _dst = Bbuf + (bufi_) * 4096 + w * 512;                    \
    GLL(_src, _dst);                                                           \
  }

#define LOAD_AF(dst_, kt_)                                                     \
  _Pragma("unroll") for (int ii = 0; ii < 2; ++ii)                             \
      _Pragma("unroll") for (int h = 0; h < 2; ++h) {                          \
    int g_ = bt * 16 + w * 2 + ii;                                             \
    dst_[ii][h] = *(const bf16x8*)(                                            \
        xbf + ((((size_t)(g_ >> 3) * 8 + (kt_)) * 8 + (g_ & 7)) * 2 + h) *     \
                  512 +                                                        \
              (size_t)l * 8);                                                  \
  }

__global__ __launch_bounds__(512, 2) void poly_gemm(
    const unsigned short* __restrict__ xbf,  // A frag-linear
    const unsigned short* __restrict__ kbf,  // B frag-linear
    const unsigned short* __restrict__ wkbf, // key_kernel frag-linear
    const float* __restrict__ key_bias,      // [K]
    const float* __restrict__ keys_map,      // [M][K]
    const float* __restrict__ biases,        // [M][U] f32
    float* __restrict__ out) {               // [B][U]
  __shared__ __align__(16) char smem[156672];

  int t = threadIdx.x, w = t >> 6, l = t & 63;
  int bid = blockIdx.x;
  int ut = bid & 7, bt = bid >> 3;  // ut: XCD-pinned kbf slice
  int b0 = bt * 256, u0 = ut * 64;
  int lane16 = l & 15, quad = l >> 4;

  unsigned short* Bbuf = (unsigned short*)smem;
  float* kvp = (float*)(smem + 65536);   // [256] stride-65 f32
  float* sSim = (float*)(smem + 132096);
  float* sBias = (float*)(smem + 148480);
  float* sKM = (float*)(smem + 152576);

  // ---- stage bias [16][64] + keys_map [16][64] (once) ----
  {
    int bi = t * 2;  // 0..1022
    *(float2*)(sBias + bi) =
        *(const float2*)(biases + (size_t)(bi >> 6) * U_SZ + u0 + (bi & 63));
    if (t < 256) ((float4*)sKM)[t] = ((const float4*)keys_map)[t];
  }

  // ---- FIX 2: issue ring slots 0-3 NOW; DMA overlaps phases A/B ----
  const unsigned short* kbf_l = kbf + (size_t)l * 8;
  STAGE(0, 0, 0);
  STAGE(1, 0, 1);
  STAGE(2, 0, 2);
  STAGE(3, 0, 3);

  // ---- phase A: keyv = xb @ Wk + key_bias -> kvp (stride 65) ----
  {
    f32x4 kacc[2][4];
#pragma unroll
    for (int ii = 0; ii < 2; ++ii)
#pragma unroll
      for (int j = 0; j < 4; ++j) kacc[ii][j] = (f32x4){0.f, 0.f, 0.f, 0.f};
    for (int kt = 0; kt < 8; ++kt) {
      bf16x8 a2[2][2];
      LOAD_AF(a2, kt);
#pragma unroll
      for (int j = 0; j < 4; ++j) {
        bf16x8 w0 = *(const bf16x8*)(wkbf + ((size_t)((kt * 4 + j) * 2 + 0) * 64 + l) * 8);
        bf16x8 w1 = *(const bf16x8*)(wkbf + ((size_t)((kt * 4 + j) * 2 + 1) * 64 + l) * 8);
#pragma unroll
        for (int ii = 0; ii < 2; ++ii) {
          kacc[ii][j] = __builtin_amdgcn_mfma_f32_16x16x32_bf16(a2[ii][0], w0, kacc[ii][j], 0, 0, 0);
          kacc[ii][j] = __builtin_amdgcn_mfma_f32_16x16x32_bf16(a2[ii][1], w1, kacc[ii][j], 0, 0, 0);
        }
      }
    }
#pragma unroll
    for (int j = 0; j < 4; ++j) {
      float bc = key_bias[j * 16 + lane16];
#pragma unroll
      for (int ii = 0; ii < 2; ++ii)
#pragma unroll
        for (int r = 0; r < 4; ++r)
          kvp[(size_t)(w * 32 + ii * 16 + quad * 4 + r) * 65 + j * 16 + lane16] =
              kacc[ii][j][r] + bc;
    }
  }
  __syncthreads();

  // ---- phase B: sim -> sSim (FIX 1: stride-65 reads, conflict-free) ----
  {
    int row = t >> 1, mg = (t & 1) * 8;
    float d2[8] = {0.f, 0.f, 0.f, 0.f, 0.f, 0.f, 0.f, 0.f};
#pragma unroll 8
    for (int k = 0; k < 64; ++k) {
      float kvv = kvp[(size_t)row * 65 + k];
#pragma unroll
      for (int q = 0; q < 8; ++q) {
        float df = kvv - sKM[(mg + q) * 64 + k];
        d2[q] += df * df;
      }
    }
#pragma unroll
    for (int q = 0; q < 8; ++q)
      sSim[(mg + q) * 256 + row] = 1.0f / (sqrtf(d2[q]) + 1.0f);
  }

  // ---- ring prologue tail ----
  bf16x8 afc[2][2], afn[2][2];
  LOAD_AF(afc, 0);
  asm volatile("s_waitcnt vmcnt(0)" ::: "memory");
  __syncthreads();

  f32x4 facc[2][4];
#pragma unroll
  for (int i = 0; i < 2; ++i)
#pragma unroll
    for (int j = 0; j < 4; ++j) facc[i][j] = (f32x4){0.f, 0.f, 0.f, 0.f};

  // ---- R6 main loop (byte-identical) ----
#pragma unroll 1
  for (int kt = 0; kt < 8; ++kt) {
#pragma unroll
    for (int mode = 0; mode < 16; ++mode) {
      const int s = kt * 16 + mode;
      {
        int mode4 = (mode + 4) & 15;
        int kt4 = (mode >= 12) ? ((kt + 1) & 7) : kt;
        STAGE(mode4, kt4, (s + 4) & 7);
      }
      if (mode == 0 && kt < 7) { LOAD_AF(afn, kt + 1); }
      if (mode < 5) {
        if (kt < 7)
          asm volatile("s_waitcnt vmcnt(8)" ::: "memory");
        else
          asm volatile("s_waitcnt vmcnt(4)" ::: "memory");
      } else {
        asm volatile("s_waitcnt vmcnt(4)" ::: "memory");
      }
      asm volatile("s_barrier" ::: "memory");

      const unsigned short* lb = Bbuf + (s & 7) * 4096;
      bf16x8 bfr[4][2];
#pragma unroll
      for (int j = 0; j < 4; ++j)
#pragma unroll
        for (int h = 0; h < 2; ++h)
          bfr[j][h] = *(const bf16x8*)(lb + (j * 2 + h) * 512 + (size_t)l * 8);

      f32x4 sv[2];
#pragma unroll
      for (int i = 0; i < 2; ++i)
        sv[i] =
            *(const f32x4*)(sSim + mode * 256 + w * 32 + i * 16 + quad * 4);

#pragma unroll
      for (int i = 0; i < 2; ++i)
#pragma unroll
        for (int j = 0; j < 4; ++j) {
          f32x4 p = __builtin_amdgcn_mfma_f32_16x16x32_bf16(
              afc[i][0], bfr[j][0], (f32x4){0.f, 0.f, 0.f, 0.f}, 0, 0, 0);
          p = __builtin_amdgcn_mfma_f32_16x16x32_bf16(afc[i][1], bfr[j][1], p,
                                                      0, 0, 0);
#pragma unroll
          for (int r = 0; r < 4; ++r) facc[i][j][r] += sv[i][r] * p[r];
        }

      if (kt == 0) {  // sim-weighted bias, once per mode
        float bbv[4];
#pragma unroll
        for (int j = 0; j < 4; ++j)
          bbv[j] = sBias[mode * 64 + j * 16 + lane16];
#pragma unroll
        for (int i = 0; i < 2; ++i)
#pragma unroll
          for (int j = 0; j < 4; ++j)
#pragma unroll
            for (int r = 0; r < 4; ++r) facc[i][j][r] += sv[i][r] * bbv[j];
      }
    }
    if (kt < 7) {
#pragma unroll
      for (int ii = 0; ii < 2; ++ii)
#pragma unroll
        for (int h = 0; h < 2; ++h) afc[ii][h] = afn[ii][h];
    }
  }

  // epilogue: drain wrap-stage DMA, direct store
  asm volatile("s_waitcnt vmcnt(0)" ::: "memory");
#pragma unroll
  for (int i = 0; i < 2; ++i)
#pragma unroll
    for (int r = 0; r < 4; ++r) {
      int row = b0 + w * 32 + i * 16 + quad * 4 + r;
      float* orow = out + (size_t)row * U_SZ + u0;
#pragma unroll
      for (int j = 0; j < 4; ++j)
        orow[j * 16 + lane16] = facc[i][j][r] * 0.0625f;
    }
}

extern "C" void kernel_launch(void* const* d_in, const int* in_sizes, int n_in,
                              void* d_out, int out_size, void* d_ws, size_t ws_size,
                              hipStream_t stream) {
  const float* x = (const float*)d_in[0];
  const float* key_kernel = (const float*)d_in[1];
  const float* key_bias = (const float*)d_in[2];
  const float* keys_map = (const float*)d_in[3];
  const float* kernels = (const float*)d_in[4];
  const float* biases = (const float*)d_in[5];
  float* out = (float*)d_out;

  // ws: xbf 8MB | kbf 8MB | wkbf 64KB
  char* p = (char*)d_ws;
  unsigned short* xbf = (unsigned short*)p;  p += (size_t)B_SZ * D_SZ * 2;
  unsigned short* kbf = (unsigned short*)p;  p += (size_t)M_SZ * U_SZ * D_SZ * 2;
  unsigned short* wkbf = (unsigned short*)p;

  prep1<<<dim3(2568), 256, 0, stream>>>(x, key_kernel, kernels, xbf, kbf, wkbf);
  poly_gemm<<<dim3(256), 512, 0, stream>>>(xbf, kbf, wkbf, key_bias, keys_map,
                                           biases, out);
}